// Round 8
// baseline (209.710 us; speedup 1.0000x reference)
//
#include <hip/hip_runtime.h>
#include <math.h>
#include <stdint.h>

#define N_NODES 50000
#define N_EDGES 600000
#define IN_DIM 128
#define HID_DIM 512
#define M_PAD 50048          // 391 * 128
#define SCAN_NB 196          // ceil(50000/256)

// prep_kernel grid partition
#define CASTX_NB 3125        // (50000*128/8)/256
#define DEG_NB   1172        // ceil(600000/2/256)
#define CASTW_NB 544         // (512*256 + 16*512)/256

typedef __bf16 bf16;
typedef __bf16 bf16x2 __attribute__((ext_vector_type(2)));
typedef __bf16 bf16x4 __attribute__((ext_vector_type(4)));
typedef __bf16 bf16x8 __attribute__((ext_vector_type(8)));
typedef float f32x4 __attribute__((ext_vector_type(4)));

#define GLDS(gp, lp) __builtin_amdgcn_global_load_lds( \
    (const __attribute__((address_space(1))) uint32_t*)(gp), \
    (__attribute__((address_space(3))) uint32_t*)(lp), 16, 0, 0)

// ---------------------------------------------------------------------------
// prep: cast_x (8 elems/thread) + degree-count (2 edges/thread) + cast_w.
// ---------------------------------------------------------------------------

__global__ __launch_bounds__(256) void prep_kernel(
    const float* __restrict__ x, bf16* __restrict__ xb,
    const int* __restrict__ dst, int* __restrict__ deg,
    const float* __restrict__ W1l, const float* __restrict__ W1r,
    const float* __restrict__ W2l, const float* __restrict__ W2r,
    bf16* __restrict__ Wt, bf16* __restrict__ W2bt) {
    int b = blockIdx.x;
    int t = threadIdx.x;
    if (b < CASTX_NB) {
        int i = b * 256 + t;
        float4 v0 = ((const float4*)x)[2 * i];
        float4 v1 = ((const float4*)x)[2 * i + 1];
        bf16x8 o = {(bf16)v0.x, (bf16)v0.y, (bf16)v0.z, (bf16)v0.w,
                    (bf16)v1.x, (bf16)v1.y, (bf16)v1.z, (bf16)v1.w};
        *(bf16x8*)(xb + (size_t)i * 8) = o;
    } else if (b < CASTX_NB + DEG_NB) {
        int e = ((b - CASTX_NB) * 256 + t) * 2;
        if (e + 1 < N_EDGES) {
            int2 d2 = *(const int2*)(dst + e);
            atomicAdd(&deg[d2.x], 1);
            atomicAdd(&deg[d2.y], 1);
        } else if (e < N_EDGES) {
            atomicAdd(&deg[dst[e]], 1);
        }
    } else {
        int idx = (b - CASTX_NB - DEG_NB) * 256 + t;
        if (idx < 512 * 256) {
            int n = idx >> 8;
            int k = idx & 255;
            float v = (k < IN_DIM) ? W1l[(size_t)k * HID_DIM + n]
                                   : W1r[(size_t)(k - IN_DIM) * HID_DIM + n];
            Wt[idx] = (bf16)v;
        } else {
            int j = idx - 512 * 256;       // < 16*512
            int n = j >> 9;                // 0..15
            int k = j & 511;
            float v = 0.f;
            if (n == 0) v = W2l[k * 2 + 0];
            else if (n == 1) v = W2l[k * 2 + 1];
            else if (n == 2) v = W2r[k * 2 + 0];
            else if (n == 3) v = W2r[k * 2 + 1];
            W2bt[j] = (bf16)v;
        }
    }
}

// ---------------------------------------------------------------------------
// Scan: per-block sums (scan1), then scan3 with in-kernel lookback.
// ---------------------------------------------------------------------------

__global__ __launch_bounds__(256) void scan1_kernel(const int* __restrict__ deg,
                                                    int* __restrict__ bsum) {
    int t = threadIdx.x;
    int i = blockIdx.x * 256 + t;
    int v = (i < N_NODES) ? deg[i] : 0;
#pragma unroll
    for (int m = 1; m < 64; m <<= 1) v += __shfl_xor(v, m);
    __shared__ int ws_[4];
    int w = t >> 6, l = t & 63;
    if (l == 0) ws_[w] = v;
    __syncthreads();
    if (t == 0) bsum[blockIdx.x] = ws_[0] + ws_[1] + ws_[2] + ws_[3];
}

__global__ __launch_bounds__(256) void scan3_kernel(const int* __restrict__ deg,
                                                    const int* __restrict__ bsum,
                                                    int* __restrict__ offsets,
                                                    int* __restrict__ cursor) {
    int t = threadIdx.x;
    int blk = blockIdx.x;
    int i = blk * 256 + t;
    int l = t & 63, w = t >> 6;
    int v = (i < N_NODES) ? deg[i] : 0;
    int inc = v;
#pragma unroll
    for (int off = 1; off < 64; off <<= 1) {
        int y = __shfl_up(inc, off);
        if (l >= off) inc += y;
    }
    __shared__ int wsum[4];
    __shared__ int lookback;
    if (l == 63) wsum[w] = inc;
    __syncthreads();
    if (t < 64) {           // wave 0: sum of bsum[0..blk-1]
        int s = 0;
        for (int u = t; u < blk; u += 64) s += bsum[u];
#pragma unroll
        for (int m = 1; m < 64; m <<= 1) s += __shfl_xor(s, m);
        if (t == 0) lookback = s;
    }
    __syncthreads();
    int add = lookback;
    for (int u = 0; u < w; ++u) add += wsum[u];
    int ex = add + inc - v;
    if (i < N_NODES) { offsets[i] = ex; cursor[i] = ex; }
    if (blk == 0 && t == 0) offsets[N_NODES] = N_EDGES;
}

__global__ void csr_fill_kernel(const int* __restrict__ src, const int* __restrict__ dst,
                                int* __restrict__ cursor, int* __restrict__ csr_src) {
    int e = (blockIdx.x * blockDim.x + threadIdx.x) * 2;
    if (e + 1 < N_EDGES) {
        int2 s2 = *(const int2*)(src + e);
        int2 d2 = *(const int2*)(dst + e);
        int p0 = atomicAdd(&cursor[d2.x], 1);
        csr_src[p0] = s2.x;
        int p1 = atomicAdd(&cursor[d2.y], 1);
        csr_src[p1] = s2.y;
    } else if (e < N_EDGES) {
        int p = atomicAdd(&cursor[dst[e]], 1);
        csr_src[p] = src[e];
    }
}

// ---------------------------------------------------------------------------
// Layer-1 mean aggregation. 16 lanes per node (16B bf16x8 per lane covers the
// 256B row), 4 nodes per wave; 8-deep unroll = 32 outstanding gathers/wave.
// ---------------------------------------------------------------------------

__global__ __launch_bounds__(256) void agg1_kernel(
    const bf16* __restrict__ xb, const int* __restrict__ offsets,
    const int* __restrict__ csr_src, bf16* __restrict__ agg1b) {
    int t = threadIdx.x;
    int w = t >> 6, l = t & 63;
    int g = l >> 4;            // node subgroup 0..3
    int sl = l & 15;           // 16B chunk index within the 256B row
    int n = blockIdx.x * 16 + w * 4 + g;
    int s0 = offsets[n], s1 = offsets[n + 1];
    float a[8] = {};
    int e = s0;
    for (; e + 8 <= s1; e += 8) {
        int idx[8];
#pragma unroll
        for (int u = 0; u < 8; ++u) idx[u] = csr_src[e + u];
        bf16x8 v[8];
#pragma unroll
        for (int u = 0; u < 8; ++u)
            v[u] = *(const bf16x8*)(xb + (size_t)idx[u] * IN_DIM + sl * 8);
#pragma unroll
        for (int u = 0; u < 8; ++u)
#pragma unroll
            for (int c = 0; c < 8; ++c) a[c] += (float)v[u][c];
    }
    if (e + 4 <= s1) {
        int idx[4];
#pragma unroll
        for (int u = 0; u < 4; ++u) idx[u] = csr_src[e + u];
        bf16x8 v[4];
#pragma unroll
        for (int u = 0; u < 4; ++u)
            v[u] = *(const bf16x8*)(xb + (size_t)idx[u] * IN_DIM + sl * 8);
#pragma unroll
        for (int u = 0; u < 4; ++u)
#pragma unroll
            for (int c = 0; c < 8; ++c) a[c] += (float)v[u][c];
        e += 4;
    }
    for (; e < s1; ++e) {
        int i0 = csr_src[e];
        bf16x8 v0 = *(const bf16x8*)(xb + (size_t)i0 * IN_DIM + sl * 8);
#pragma unroll
        for (int c = 0; c < 8; ++c) a[c] += (float)v0[c];
    }
    float inv = 1.0f / fmaxf((float)(s1 - s0), 1.0f);
    bf16x8 o;
#pragma unroll
    for (int c = 0; c < 8; ++c) o[c] = (bf16)(a[c] * inv);
    *(bf16x8*)(agg1b + (size_t)n * IN_DIM + sl * 8) = o;
}

// ---------------------------------------------------------------------------
// GEMM1 + MFMA z-epilogue, software-pipelined (BK=32 x 8, double-buffered).
// h = relu([agg1b|xb] @ Wt^T + b1) lives only in LDS; z-projection via a
// second MFMA pass against W2bt. No h in HBM, no atomics.
// grid (4, 391): col-blocks sharing A are dispatch-adjacent -> A from L2 once.
// ---------------------------------------------------------------------------

__global__ __launch_bounds__(256) void gemm1_kernel(
    const bf16* __restrict__ agg1b, const bf16* __restrict__ xb,
    const bf16* __restrict__ Wt, const float* __restrict__ b1,
    const bf16* __restrict__ W2bt, float* __restrict__ zpart) {
    __shared__ __align__(16) char smem[128 * 136 * 2];
    bf16 (*As)[128][32] = (bf16(*)[128][32])smem;
    bf16 (*Bs)[128][32] = (bf16(*)[128][32])(smem + 16384);
    bf16 (*Hs)[136] = (bf16(*)[136])smem;
    int tid = threadIdx.x;
    int w = tid >> 6;
    int lane = tid & 63;
    int q = lane >> 4, rr = lane & 15;
    int cb = blockIdx.x;           // 0..3
    int n0 = cb * 128;
    int row0 = blockIdx.y * 128;   // 0..390
    int wm = (w & 1) * 64, wn = (w >> 1) * 64;
    int lr = lane >> 2;            // staging row 0..15
    int lc = (lane & 3) * 8;       // staging k-offset (elems)

    auto stage = [&](int ki) {
        const bf16* Asrc;
        int kb;
        if (ki < 4) { Asrc = agg1b; kb = ki * 32; }
        else        { Asrc = xb;    kb = ki * 32 - IN_DIM; }
        int kw = ki * 32;
        int buf = ki & 1;
#pragma unroll
        for (int j = 0; j < 2; ++j) {
            int r = w * 32 + j * 16 + lr;
            GLDS(Asrc + (size_t)(row0 + r) * IN_DIM + kb + lc,
                 &As[buf][w * 32 + j * 16][0]);
            GLDS(Wt + (size_t)(n0 + r) * 256 + kw + lc,
                 &Bs[buf][w * 32 + j * 16][0]);
        }
    };

    f32x4 acc[4][4] = {};
    stage(0);
#pragma unroll
    for (int ki = 0; ki < 8; ++ki) {
        __syncthreads();                 // drains stage(ki); guards buf reuse
        if (ki + 1 < 8) stage(ki + 1);   // prefetch overlaps compute below
        int buf = ki & 1;
        bf16x8 af[4], bfr[4];
#pragma unroll
        for (int i = 0; i < 4; ++i)
            af[i] = *(const bf16x8*)&As[buf][wm + i * 16 + rr][q * 8];
#pragma unroll
        for (int j = 0; j < 4; ++j)
            bfr[j] = *(const bf16x8*)&Bs[buf][wn + j * 16 + rr][q * 8];
#pragma unroll
        for (int i = 0; i < 4; ++i)
#pragma unroll
            for (int j = 0; j < 4; ++j)
                acc[i][j] = __builtin_amdgcn_mfma_f32_16x16x32_bf16(
                    af[i], bfr[j], acc[i][j], 0, 0, 0);
    }
    __syncthreads();   // all compute done before Hs aliases As/Bs
    // ---- stage h tile (relu'd, bf16) into LDS
    float bias[4];
#pragma unroll
    for (int j = 0; j < 4; ++j) bias[j] = b1[n0 + wn + j * 16 + rr];
#pragma unroll
    for (int i = 0; i < 4; ++i) {
#pragma unroll
        for (int rg = 0; rg < 4; ++rg) {
            int mrow = wm + i * 16 + q * 4 + rg;
#pragma unroll
            for (int j = 0; j < 4; ++j)
                Hs[mrow][wn + j * 16 + rr] =
                    (bf16)fmaxf(acc[i][j][rg] + bias[j], 0.f);
        }
    }
    __syncthreads();
    // ---- z projection: [128 rows x K=128] @ W2bt^T (16 cols, 4 used)
    bf16x8 wf[4];
#pragma unroll
    for (int ks = 0; ks < 4; ++ks)
        wf[ks] = *(const bf16x8*)(W2bt + (size_t)rr * 512 + n0 + ks * 32 + q * 8);
    f32x4 zacc[2] = {};
#pragma unroll
    for (int mt = 0; mt < 2; ++mt)
#pragma unroll
        for (int ks = 0; ks < 4; ++ks) {
            bf16x8 afz = *(const bf16x8*)&Hs[w * 32 + mt * 16 + rr][ks * 32 + q * 8];
            zacc[mt] = __builtin_amdgcn_mfma_f32_16x16x32_bf16(
                afz, wf[ks], zacc[mt], 0, 0, 0);
        }
    if (rr < 4) {
#pragma unroll
        for (int mt = 0; mt < 2; ++mt)
#pragma unroll
            for (int rg = 0; rg < 4; ++rg) {
                int grow = row0 + w * 32 + mt * 16 + q * 4 + rg;
                zpart[(size_t)grow * 16 + cb * 4 + rr] = zacc[mt][rg];
            }
    }
}

// ---------------------------------------------------------------------------
// zsum: z[n][0..3] = sum of the 4 col-block partials.
// ---------------------------------------------------------------------------

__global__ __launch_bounds__(256) void zsum_kernel(const float* __restrict__ zpart,
                                                   float* __restrict__ z) {
    int n = blockIdx.x * blockDim.x + threadIdx.x;
    if (n >= N_NODES) return;
    const float4* p = (const float4*)(zpart + (size_t)n * 16);
    float4 a = p[0], b = p[1], c = p[2], d = p[3];
    float4 o = {a.x + b.x + c.x + d.x, a.y + b.y + c.y + d.y,
                a.z + b.z + c.z + d.z, a.w + b.w + c.w + d.w};
    *(float4*)(z + (size_t)n * 4) = o;
}

// ---------------------------------------------------------------------------
// final: out[n] = log_softmax(mean_e z[src][0..1] + b2 + z[n][2..3])
// 8 lanes per node, each lane takes every-8th edge; 3-level shfl reduce.
// ---------------------------------------------------------------------------

__global__ __launch_bounds__(256) void final_kernel(
    const float* __restrict__ z, const int* __restrict__ offsets,
    const int* __restrict__ csr_src, const float* __restrict__ b2,
    float* __restrict__ out) {
    int t = threadIdx.x;
    int w = t >> 6, l = t & 63;
    int g = l >> 3;            // node subgroup 0..7
    int sl = l & 7;            // edge lane within node
    int n = blockIdx.x * 32 + w * 8 + g;
    bool valid = (n < N_NODES);
    int s0 = valid ? offsets[n] : 0;
    int s1 = valid ? offsets[n + 1] : 0;
    float a0 = 0.f, a1 = 0.f;
    for (int e = s0 + sl; e < s1; e += 8) {
        int s = csr_src[e];
        float2 v = *(const float2*)(z + (size_t)s * 4);
        a0 += v.x;
        a1 += v.y;
    }
#pragma unroll
    for (int m = 1; m < 8; m <<= 1) {
        a0 += __shfl_xor(a0, m);
        a1 += __shfl_xor(a1, m);
    }
    if (valid && sl == 0) {
        float inv = 1.0f / fmaxf((float)(s1 - s0), 1.0f);
        float2 zs = *(const float2*)(z + (size_t)n * 4 + 2);
        float o0 = a0 * inv + b2[0] + zs.x;
        float o1 = a1 * inv + b2[1] + zs.y;
        float m = fmaxf(o0, o1);
        float lse = logf(expf(o0 - m) + expf(o1 - m));
        float2 o = {o0 - m - lse, o1 - m - lse};
        *(float2*)(out + (size_t)n * 2) = o;
    }
}

// ---------------------------------------------------------------------------

extern "C" void kernel_launch(void* const* d_in, const int* in_sizes, int n_in,
                              void* d_out, int out_size, void* d_ws, size_t ws_size,
                              hipStream_t stream) {
    const float* x   = (const float*)d_in[0];
    const float* W1l = (const float*)d_in[1];
    const float* b1  = (const float*)d_in[2];
    const float* W1r = (const float*)d_in[3];
    const float* W2l = (const float*)d_in[4];
    const float* b2  = (const float*)d_in[5];
    const float* W2r = (const float*)d_in[6];
    const int* edge  = (const int*)d_in[7];
    const int* src = edge;
    const int* dst = edge + N_EDGES;
    float* out = (float*)d_out;

    char* ws = (char*)d_ws;
    size_t off = 0;
    auto alloc = [&](size_t bytes) -> void* {
        void* p = ws + off;
        off += (bytes + 255) & ~(size_t)255;
        return p;
    };
    int* deg     = (int*)alloc((size_t)N_NODES * 4);
    int* offsets = (int*)alloc((size_t)(N_NODES + 1) * 4);
    int* cursor  = (int*)alloc((size_t)N_NODES * 4);
    int* csr_src = (int*)alloc((size_t)N_EDGES * 4);
    int* bsum    = (int*)alloc((size_t)SCAN_NB * 4);
    bf16* xb     = (bf16*)alloc((size_t)M_PAD * IN_DIM * 2);
    bf16* agg1b  = (bf16*)alloc((size_t)M_PAD * IN_DIM * 2);
    bf16* Wt     = (bf16*)alloc((size_t)HID_DIM * 256 * 2);
    bf16* W2bt   = (bf16*)alloc((size_t)16 * HID_DIM * 2);
    float* zpart = (float*)alloc((size_t)M_PAD * 16 * 4);
    float* z     = (float*)alloc((size_t)N_NODES * 4 * 4);

    hipMemsetAsync(deg, 0, (size_t)N_NODES * 4, stream);
    prep_kernel<<<CASTX_NB + DEG_NB + CASTW_NB, 256, 0, stream>>>(
        x, xb, dst, deg, W1l, W1r, W2l, W2r, Wt, W2bt);
    scan1_kernel<<<SCAN_NB, 256, 0, stream>>>(deg, bsum);
    scan3_kernel<<<SCAN_NB, 256, 0, stream>>>(deg, bsum, offsets, cursor);
    csr_fill_kernel<<<(N_EDGES / 2 + 255) / 256, 256, 0, stream>>>(
        src, dst, cursor, csr_src);
    agg1_kernel<<<N_NODES / 16, 256, 0, stream>>>(xb, offsets, csr_src, agg1b);
    gemm1_kernel<<<dim3(4, M_PAD / 128), 256, 0, stream>>>(
        agg1b, xb, Wt, b1, W2bt, zpart);
    zsum_kernel<<<(N_NODES + 255) / 256, 256, 0, stream>>>(zpart, z);
    final_kernel<<<(N_NODES + 31) / 32, 256, 0, stream>>>(z, offsets, csr_src, b2, out);
}